// Round 3
// baseline (1016.017 us; speedup 1.0000x reference)
//
#include <hip/hip_runtime.h>

// Problem constants (fixed by the reference)
#define HID 2048
#define SEQ 2048
#define NB 2
#define NHD 16
#define HD 128
#define FF 5632
#define MROWS 4096  // NB*SEQ

typedef __bf16 bf16x8 __attribute__((ext_vector_type(8)));
typedef float f32x4 __attribute__((ext_vector_type(4)));
typedef unsigned short u16;
typedef unsigned int u32;
typedef unsigned long long u64;

__device__ __forceinline__ u16 f2bf(float f) {
  u32 u = __float_as_uint(f);
  u += 0x7fffu + ((u >> 16) & 1u);   // RNE
  return (u16)(u >> 16);
}
__device__ __forceinline__ float bf2f(u16 h) {
  return __uint_as_float(((u32)h) << 16);
}
__device__ __forceinline__ void gld16(const void* g, void* l) {
  // async global->LDS, 16B per lane; LDS dest = wave-uniform base + lane*16
  __builtin_amdgcn_global_load_lds((__attribute__((address_space(1))) void*)g,
                                   (__attribute__((address_space(3))) void*)l, 16, 0, 0);
}

// ---------------- RMSNorm: fp32 [rows][2048] -> bf16 ----------------
__global__ __launch_bounds__(256) void rmsnorm_k(const float* __restrict__ x,
                                                 const float* __restrict__ sc,
                                                 u16* __restrict__ out) {
  __shared__ float red[4];
  const int row = blockIdx.x, t = threadIdx.x;
  const float4* xr = (const float4*)(x + (size_t)row * HID);
  float4 a = xr[t], b = xr[t + 256];
  float ss = a.x*a.x + a.y*a.y + a.z*a.z + a.w*a.w
           + b.x*b.x + b.y*b.y + b.z*b.z + b.w*b.w;
#pragma unroll
  for (int o = 1; o < 64; o <<= 1) ss += __shfl_xor(ss, o);
  if ((t & 63) == 0) red[t >> 6] = ss;
  __syncthreads();
  float tot = red[0] + red[1] + red[2] + red[3];
  float r = rsqrtf(tot * (1.0f / HID) + 1e-5f);
  const float4* scp = (const float4*)sc;
  float4 s0 = scp[t], s1 = scp[t + 256];
  u32 p0 = (u32)f2bf(a.x*r*s0.x) | ((u32)f2bf(a.y*r*s0.y) << 16);
  u32 p1 = (u32)f2bf(a.z*r*s0.z) | ((u32)f2bf(a.w*r*s0.w) << 16);
  u32 p2 = (u32)f2bf(b.x*r*s1.x) | ((u32)f2bf(b.y*r*s1.y) << 16);
  u32 p3 = (u32)f2bf(b.z*r*s1.z) | ((u32)f2bf(b.w*r*s1.w) << 16);
  u32* op = (u32*)(out + (size_t)row * HID);
  op[t*2] = p0; op[t*2+1] = p1;
  op[512 + t*2] = p2; op[512 + t*2 + 1] = p3;
}

// ------------- transpose+convert: fp32 W[R][C] -> bf16 Wt[C][R] -------------
__global__ __launch_bounds__(256) void transpose_cvt_k(const float* __restrict__ W,
                                                       u16* __restrict__ Wt,
                                                       int R, int C) {
  __shared__ float tile[32][33];
  const int tx = threadIdx.x & 31, ty = threadIdx.x >> 5;
  const int bc = blockIdx.x * 32, br = blockIdx.y * 32;
#pragma unroll
  for (int i = 0; i < 4; ++i)
    tile[ty + i*8][tx] = W[(size_t)(br + ty + i*8) * C + bc + tx];
  __syncthreads();
#pragma unroll
  for (int i = 0; i < 4; ++i)
    Wt[(size_t)(bc + ty + i*8) * R + br + tx] = f2bf(tile[tx][ty + i*8]);
}

// ---------------- RoPE in place on [B*H][S][D] bf16 ----------------
__global__ __launch_bounds__(256) void rope_k(u16* __restrict__ qk, const int* __restrict__ pos) {
  const u32 i = blockIdx.x * 256 + threadIdx.x;  // B*H*S*64 pairs
  const int d2 = i & 63;
  const int s = (i >> 6) & 2047;
  const int bh = i >> 17;
  const int b = bh >> 4;
  const float p = (float)pos[(size_t)b * SEQ + s];
  // inv_freq = theta^(-d2/64) = 2^(-d2 * log2(theta)/64)
  const float ang = p * exp2f(-(float)d2 * 0.2958057589f);
  float sv, cv;
  sincosf(ang, &sv, &cv);
  u32* ptr = (u32*)(qk + ((size_t)bh * SEQ + s) * HD) + d2;
  u32 u = *ptr;
  float x0 = bf2f((u16)(u & 0xffff)), x1 = bf2f((u16)(u >> 16));
  float o0 = x0 * cv - x1 * sv;
  float o1 = x1 * cv + x0 * sv;
  *ptr = (u32)f2bf(o0) | ((u32)f2bf(o1) << 16);
}

// ============ GEMM 256x256 tile, BK=64, 8 waves, 4-phase counted-vmcnt ============
// C[M][N] = A[M][K] * Bt[N][K]^T, bf16 in, fp32 acc. K % 64 == 0, M,N % 256 == 0.
// Waves: wr = wid>>2 (2 M-groups), wc = wid&3 (4 N-groups). Fragment rows are
// INTERLEAVED at 16 granularity: A row(mi) = mi*32 + wr*16 + lr (mi 0..7),
// B row(ni) = ni*64 + wc*16 + lr (ni 0..3) -> quadrant (a,b) touches only
// A-half a / B-half b of the K-tile, making half-tiles phase-local.
// LDS: A,B tiles [256][64] bf16, double-buffered = 128 KiB. T2 XOR swizzle
// byte ^= ((byte>>9)&1)<<5, applied on the global SOURCE (linear LDS dest,
// rule m104/m173) and on ds_read addresses.
// Schedule per K-tile t (buffers: read buf, stage nb=buf^1 with tile t+1):
//   p0: issue A0' | vmcnt(6) barrier | read A0,B0 | mfma(0,0)
//   p1: issue B0' | vmcnt(6) barrier | read B1    | mfma(0,1)
//   p2: issue B1' | vmcnt(6) barrier | read A1    | mfma(1,1)
//   p3: issue A1' |                  (reg reuse)  | mfma(1,0)
// vmcnt ledger (2 loads/half-group/thread, issue order A0,B0,B1,A1):
// entering p0 outstanding = {A0..A1}=8, +2 issued -> keep newest 6 retires
// this tile's A0,B0; p1/p2 analogous. Peeled last tile: drain 4,2,0.
// EPI: 1 = fused QKV scatter (outp=qb, K at +MROWS*HID, V^T at +2*MROWS*HID);
//      2 = fp32 out = addsrc + acc; 3 = bf16 silu(acc); 4 = bf16 mulsrc*acc.
#define VMW(N) asm volatile("s_waitcnt vmcnt(" #N ")" ::: "memory")
#define BARR() do { __builtin_amdgcn_s_barrier(); __builtin_amdgcn_sched_barrier(0); } while (0)

#define STAGE_A(NB, H) do { \
  gld16(ap + (size_t)((H)*128) * K,      &Ab[NB][(H)*8192 + wid*512]); \
  gld16(ap + (size_t)((H)*128 + 64) * K, &Ab[NB][(H)*8192 + 4096 + wid*512]); \
} while (0)
#define STAGE_B(NB, H) do { \
  gld16(bp + (size_t)((H)*128) * K,      &Bb[NB][(H)*8192 + wid*512]); \
  gld16(bp + (size_t)((H)*128 + 64) * K, &Bb[NB][(H)*8192 + 4096 + wid*512]); \
} while (0)
#define READ_A(BF, AH) do { \
  const char* pa_ = (const char*)Ab[BF] + (AH)*16384 + arow; \
  av[0][0] = *(const bf16x8*)(pa_ + 0*4096 + ck0); av[0][1] = *(const bf16x8*)(pa_ + 0*4096 + ck1); \
  av[1][0] = *(const bf16x8*)(pa_ + 1*4096 + ck0); av[1][1] = *(const bf16x8*)(pa_ + 1*4096 + ck1); \
  av[2][0] = *(const bf16x8*)(pa_ + 2*4096 + ck0); av[2][1] = *(const bf16x8*)(pa_ + 2*4096 + ck1); \
  av[3][0] = *(const bf16x8*)(pa_ + 3*4096 + ck0); av[3][1] = *(const bf16x8*)(pa_ + 3*4096 + ck1); \
} while (0)
#define READ_B(BF, BH) do { \
  const char* pb_ = (const char*)Bb[BF] + (BH)*16384 + brow; \
  bv[(BH)*2+0][0] = *(const bf16x8*)(pb_ + 0*8192 + ck0); bv[(BH)*2+0][1] = *(const bf16x8*)(pb_ + 0*8192 + ck1); \
  bv[(BH)*2+1][0] = *(const bf16x8*)(pb_ + 1*8192 + ck0); bv[(BH)*2+1][1] = *(const bf16x8*)(pb_ + 1*8192 + ck1); \
} while (0)
#define MMAQ(AH, BH) do { \
  __builtin_amdgcn_s_setprio(1); \
  _Pragma("unroll") \
  for (int kk_ = 0; kk_ < 2; ++kk_) \
    _Pragma("unroll") \
    for (int m_ = 0; m_ < 4; ++m_) \
      _Pragma("unroll") \
      for (int n_ = 0; n_ < 2; ++n_) \
        acc[(AH)*4+m_][(BH)*2+n_] = __builtin_amdgcn_mfma_f32_16x16x32_bf16( \
            av[m_][kk_], bv[(BH)*2+n_][kk_], acc[(AH)*4+m_][(BH)*2+n_], 0, 0, 0); \
  __builtin_amdgcn_s_setprio(0); \
} while (0)

template <int EPI>
__global__ __launch_bounds__(512, 2) void gemm256_k(const u16* __restrict__ A,
                                                    const u16* __restrict__ Bt,
                                                    int N, int K,
                                                    const float* __restrict__ addsrc,
                                                    const u16* __restrict__ mulsrc,
                                                    void* __restrict__ outp) {
  __shared__ __align__(16) u16 Ab[2][16384];
  __shared__ __align__(16) u16 Bb[2][16384];
  const int tid = threadIdx.x, lane = tid & 63, wid = tid >> 6;
  const int lr = lane & 15, lg = lane >> 4;
  const int wr = wid >> 2, wc = wid & 3;

  // XCD swizzle (all grids have nwg % 8 == 0): XCD x gets a contiguous chunk
  // of n-major tile order -> A-panel reuse within an XCD L2.
  const int gx = gridDim.x;
  int bid = blockIdx.y * gx + blockIdx.x;
  const int q8 = (gx * gridDim.y) >> 3;
  bid = (bid & 7) * q8 + (bid >> 3);
  const int mt = (bid / gx) * 256, nt = (bid % gx) * 256;

  const f32x4 fz = {0.f, 0.f, 0.f, 0.f};
  f32x4 acc[8][4];
#pragma unroll
  for (int i = 0; i < 8; ++i)
#pragma unroll
    for (int j = 0; j < 4; ++j) acc[i][j] = fz;

  // staging: thread covers LDS bytes tid*16 of each 8KB issue-region.
  // row = h*128 + j*64 + (tid>>3); src col pre-swizzled (bit2 of row = bit2 of tid>>3)
  const int srow = tid >> 3;
  const int scol = ((((tid & 7) * 16) ^ (((srow >> 2) & 1) << 5)) >> 1);
  const u16* ap = A  + (size_t)(mt + srow) * K + scol;
  const u16* bp = Bt + (size_t)(nt + srow) * K + scol;

  // ds_read addressing: frag byte = row*128 + ((kk*64 + lg*16) ^ sw(lr))
  const int arow = (wr * 16 + lr) * 128;
  const int brow = (wc * 16 + lr) * 128;
  const int swl = ((lr >> 2) & 1) << 5;
  const int ck0 = (lg * 16) ^ swl;
  const int ck1 = (64 + lg * 16) ^ swl;

  bf16x8 av[4][2], bv[4][2];

  // prologue: stage tile 0 (issue order A0,B0,B1,A1 — ledger depends on it)
  STAGE_A(0, 0); STAGE_B(0, 0); STAGE_B(0, 1); STAGE_A(0, 1);
  ap += 64; bp += 64;

  const int ntk = K >> 6;
  int buf = 0;
  for (int t = 0; t < ntk - 1; ++t) {
    const int nb = buf ^ 1;
    STAGE_A(nb, 0);  VMW(6); BARR();
    READ_A(buf, 0);  READ_B(buf, 0);  MMAQ(0, 0);
    STAGE_B(nb, 0);  VMW(6); BARR();
    READ_B(buf, 1);  MMAQ(0, 1);
    STAGE_B(nb, 1);  VMW(6); BARR();
    READ_A(buf, 1);  MMAQ(1, 1);
    STAGE_A(nb, 1);
    MMAQ(1, 0);
    ap += 64; bp += 64;
    buf = nb;
  }
  // peeled last tile: drain counts
  VMW(4); BARR();
  READ_A(buf, 0); READ_B(buf, 0); MMAQ(0, 0);
  VMW(2); BARR();
  READ_B(buf, 1); MMAQ(0, 1);
  VMW(0); BARR();
  READ_A(buf, 1); MMAQ(1, 1);
  MMAQ(1, 0);

  // ---- epilogue ----
#pragma unroll
  for (int mi = 0; mi < 8; ++mi) {
#pragma unroll
    for (int ni = 0; ni < 4; ++ni) {
      const int gr0 = mt + mi * 32 + wr * 16 + lg * 4;
      const int gc = nt + ni * 64 + wc * 16 + lr;
      f32x4 v = acc[mi][ni];
      if (EPI == 1) {
        const int which = gc >> 11;        // 0=Q, 1=K, 2=V (uniform per block)
        const int c2 = gc & 2047;
        const int hh = c2 >> 7, d = c2 & 127;
        if (which < 2) {
          u16* dst = (u16*)outp + (size_t)which * ((size_t)MROWS * HID);
#pragma unroll
          for (int r = 0; r < 4; ++r) {
            const int gr = gr0 + r;
            const int b = gr >> 11, s = gr & 2047;
            dst[((((size_t)(b * NHD + hh)) * SEQ + s) << 7) + d] = f2bf(v[r]);
          }
        } else {
          u16* dst = (u16*)outp + (size_t)2 * ((size_t)MROWS * HID);
          const int b = gr0 >> 11, s0 = gr0 & 2047;
          u64 pk = (u64)f2bf(v[0]) | ((u64)f2bf(v[1]) << 16)
                 | ((u64)f2bf(v[2]) << 32) | ((u64)f2bf(v[3]) << 48);
          *(u64*)(dst + ((((size_t)(b * NHD + hh)) * HD + d) << 11) + s0) = pk;
        }
      } else {
#pragma unroll
        for (int r = 0; r < 4; ++r) {
          const int gr = gr0 + r;
          const float val = v[r];
          if (EPI == 2) {
            const size_t o = (size_t)gr * N + gc;
            ((float*)outp)[o] = addsrc[o] + val;
          } else if (EPI == 3) {
            const size_t o = (size_t)gr * N + gc;
            ((u16*)outp)[o] = f2bf(val / (1.f + __expf(-val)));
          } else if (EPI == 4) {
            const size_t o = (size_t)gr * N + gc;
            ((u16*)outp)[o] = f2bf(bf2f(mulsrc[o]) * val);
          }
        }
      }
    }
  }
}

// ---------------- Flash attention, causal, bf16 ----------------
// Q,K in [B*H][S][D]; V in [B*H][D][S] (transposed by gemm epilogue).
// 512 blocks x 4 waves; block handles q-tile pair (p, 31-p) of one head ->
// uniform 33 key-tiles/block. K/V^T double-buffered LDS via global_load_lds
// with XOR-swizzled source, swizzled ds_reads. 2-phase, counted prefetch.
#define ATT_SW(row) (((row) & 7) << 4)

__device__ __forceinline__ void att_stage(const u16* __restrict__ Kp,
                                          const u16* __restrict__ Vp,
                                          int kt, char* kb, char* vb,
                                          int tid, int wid) {
  // K tile [64 key][128 d] u16 = 16KB: 16 chunks(16B)/row
#pragma unroll
  for (int j = 0; j < 4; ++j) {
    const int c = j * 256 + tid;
    const int row = c >> 4;
    const int scb = ((c & 15) << 4) ^ ATT_SW(row);
    gld16(Kp + (size_t)(kt + row) * HD + (scb >> 1), kb + j * 4096 + wid * 1024);
  }
  // V^T tile [128 d][64 key] u16 = 16KB: 8 chunks/row
#pragma unroll
  for (int j = 0; j < 4; ++j) {
    const int c = j * 256 + tid;
    const int row = c >> 3;
    const int scb = ((c & 7) << 4) ^ ATT_SW(row);
    gld16(Vp + (size_t)row * SEQ + kt + (scb >> 1), vb + j * 4096 + wid * 1024);
  }
}

__global__ __launch_bounds__(256, 2) void attn_k(const u16* __restrict__ Q,
                                                 const u16* __restrict__ Kg,
                                                 const u16* __restrict__ Vtg,
                                                 u16* __restrict__ out) {
  __shared__ __align__(16) char Kb[2][16384];
  __shared__ __align__(16) char Vb[2][16384];
  __shared__ __align__(16) u16 Pl[4][16 * 72];  // per-wave P [q][key], stride 72
  const int tid = threadIdx.x, lane = tid & 63, wid = tid >> 6;
  const int lr = lane & 15, lg = lane >> 4;
  int wg = blockIdx.x;
  wg = (wg & 7) * 64 + (wg >> 3);
  const int bh = wg >> 4, pr = wg & 15;
  const size_t bhoff = (size_t)bh * SEQ * HD;
  const u16* Qp = Q + bhoff;
  const u16* Kp = Kg + bhoff;
  const u16* Vp = Vtg + bhoff;   // [D][S]
  const int bb = bh >> 4, hh = bh & 15;
  u16* Pw = Pl[wid];
  const int sw = ATT_SW(lr);
  const float scale = 0.08838834764831845f;  // 1/sqrt(128)
  const f32x4 fz = {0.f, 0.f, 0.f, 0.f};

  for (int side = 0; side < 2; ++side) {
    const int qt = side ? (31 - pr) : pr;
    const int qrow0 = qt * 64 + wid * 16;

    bf16x8 qf[4];
#pragma unroll
    for (int t = 0; t < 4; ++t)
      qf[t] = *(const bf16x8*)(Qp + (size_t)(qrow0 + lr) * HD + t * 32 + lg * 8);

    f32x4 o[8];
#pragma unroll
    for (int i = 0; i < 8; ++i) o[i] = fz;
    float mrun[4] = {-1e30f, -1e30f, -1e30f, -1e30f};
    float lrun[4] = {0.f, 0.f, 0.f, 0.f};

    const int kend = qt * 64 + 64;
    int cur = 0;
    att_stage(Kp, Vp, 0, Kb[0], Vb[0], tid, wid);
    __syncthreads();  // drains vmcnt -> tile 0 staged

    for (int kt = 0; kt < kend; kt += 64) {
      if (kt + 64 < kend)
        att_stage(Kp, Vp, kt + 64, Kb[cur ^ 1], Vb[cur ^ 1], tid, wid);
      const char* kbuf = Kb[cur];
      const char* vbuf = Vb[cur];

      // ---- QK^T from swizzled LDS ----
      f32x4 sc2[4];
#pragma unroll
      for (int nh = 0; nh < 4; ++nh) {
        f32x4 s = fz;
#pragma unroll
        for (int t = 0; t < 4; ++t) {
          bf16x8 kf = *(const bf16x8*)(kbuf + (nh * 16 + lr) * 256 + ((t * 64 + lg * 16) ^ sw));
          s = __builtin_amdgcn_mfma_f32_16x16x32_bf16(qf[t], kf, s, 0, 0, 0);
        }
        sc2[nh] = s;
      }

      // ---- online softmax over 64 keys (16-lane groups hold keys) ----
      float pv[4][4], alpha[4];
#pragma unroll
      for (int r = 0; r < 4; ++r) {
        const int qrow = qrow0 + lg * 4 + r;
        float s0 = sc2[0][r] * scale;
        float s1 = sc2[1][r] * scale;
        float s2 = sc2[2][r] * scale;
        float s3 = sc2[3][r] * scale;
        if (kt + lr > qrow)      s0 = -1e30f;
        if (kt + 16 + lr > qrow) s1 = -1e30f;
        if (kt + 32 + lr > qrow) s2 = -1e30f;
        if (kt + 48 + lr > qrow) s3 = -1e30f;
        float mx = fmaxf(fmaxf(s0, s1), fmaxf(s2, s3));
        mx = fmaxf(mx, __shfl_xor(mx, 1));
        mx = fmaxf(mx, __shfl_xor(mx, 2));
        mx = fmaxf(mx, __shfl_xor(mx, 4));
        mx = fmaxf(mx, __shfl_xor(mx, 8));
        const float mn = fmaxf(mrun[r], mx);
        const float p0 = __expf(s0 - mn), p1 = __expf(s1 - mn);
        const float p2 = __expf(s2 - mn), p3 = __expf(s3 - mn);
        float ts = p0 + p1 + p2 + p3;
        ts += __shfl_xor(ts, 1);
        ts += __shfl_xor(ts, 2);
        ts += __shfl_xor(ts, 4);
        ts += __shfl_xor(ts, 8);
        const float al = __expf(mrun[r] - mn);
        alpha[r] = al;
        lrun[r] = lrun[r] * al + ts;
        mrun[r] = mn;
        pv[0][r] = p0; pv[1][r] = p1; pv[2][r] = p2; pv[3][r] = p3;
      }
#pragma unroll
      for (int i = 0; i < 8; ++i) {
        o[i][0] *= alpha[0]; o[i][1] *= alpha[1];
        o[i][2] *= alpha[2]; o[i][3] *= alpha[3];
      }

      // ---- P -> LDS (lane redistribution for MFMA A-operand) ----
#pragma unroll
      for (int nh = 0; nh < 4; ++nh)
#pragma unroll
        for (int r = 0; r < 4; ++r)
          Pw[(lg * 4 + r) * 72 + nh * 16 + lr] = f2bf(pv[nh][r]);
      asm volatile("s_waitcnt lgkmcnt(0)\n" ::: "memory");  // P write -> read, same wave
      const bf16x8 pf0 = *(const bf16x8*)(Pw + lr * 72 + lg * 8);
      const bf16x8 pf1 = *(const bf16x8*)(Pw + lr * 72 + 32 + lg * 8);

      // ---- PV from swizzled V^T LDS ----
#pragma unroll
      for (int nt2 = 0; nt2 < 8; ++nt2) {
        const char* vr = vbuf + (nt2 * 16 + lr) * 128;
        bf16x8 v0 = *(const bf16x8*)(vr + ((lg * 16) ^ sw));
        bf16x8 v1 = *(const bf16x8*)(vr + ((64 + lg * 16) ^ sw));
        o[nt2] = __builtin_amdgcn_mfma_f32_16x16x32_bf16(pf0, v0, o[nt2], 0, 0, 0);
        o[nt2] = __builtin_amdgcn_mfma_f32_16x16x32_bf16(pf1, v1, o[nt2], 0, 0, 0);
      }
      __syncthreads();  // next tile staged + buf free for overwrite
      cur ^= 1;
    }

    // ---- epilogue: normalize + store 16 q-rows/wave ----
#pragma unroll
    for (int r = 0; r < 4; ++r) {
      const int q = qrow0 + lg * 4 + r;
      const float inv = 1.f / lrun[r];
      u16* op = out + ((size_t)(bb * SEQ + q)) * HID + hh * HD + lr;
#pragma unroll
      for (int nt2 = 0; nt2 < 8; ++nt2)
        op[nt2 * 16] = f2bf(o[nt2][r] * inv);
    }
  }
}

extern "C" void kernel_launch(void* const* d_in, const int* in_sizes, int n_in,
                              void* d_out, int out_size, void* d_ws, size_t ws_size,
                              hipStream_t stream) {
  (void)in_sizes; (void)n_in; (void)out_size; (void)ws_size;
  const float* x   = (const float*)d_in[0];
  const int*   pos = (const int*)d_in[1];
  // d_in[2] = mask: causal tril by construction — handled analytically
  const float* wq  = (const float*)d_in[3];
  const float* wk  = (const float*)d_in[4];
  const float* wv  = (const float*)d_in[5];
  const float* wo  = (const float*)d_in[6];
  const float* asc = (const float*)d_in[7];
  const float* fsc = (const float*)d_in[8];
  const float* w1  = (const float*)d_in[9];
  const float* w3  = (const float*)d_in[10];
  const float* w2  = (const float*)d_in[11];
  float* out = (float*)d_out;

  // workspace carve (~136 MB)
  char* ws = (char*)d_ws;
  u16* qb = (u16*)ws; ws += (size_t)MROWS * HID * 2;   // Q [B,H,S,D]
  u16* kb = (u16*)ws; ws += (size_t)MROWS * HID * 2;   // K [B,H,S,D]  (must follow qb)
  u16* vb = (u16*)ws; ws += (size_t)MROWS * HID * 2;   // V^T [B,H,D,S] (must follow kb)
  u16* xb = (u16*)ws; ws += (size_t)MROWS * HID * 2;   // x_norm / attn_out / ff (bf16)
  u16* gb = (u16*)ws; ws += (size_t)MROWS * FF * 2;    // g1 / u (bf16)
  u16* wb = (u16*)ws; ws += (size_t)FF * HID * 2;      // current transposed weight (bf16)
  // fused QKV weight [6144][2048] overlaps gb (dead until FFN phase): 25.2MB <= 46.1MB
  u16* wqkvT = gb;

  dim3 b256(256), b512(512);

  rmsnorm_k<<<MROWS, b256, 0, stream>>>(x, asc, xb);

  transpose_cvt_k<<<dim3(HID/32, HID/32), b256, 0, stream>>>(wq, wqkvT, HID, HID);
  transpose_cvt_k<<<dim3(HID/32, HID/32), b256, 0, stream>>>(wk, wqkvT + (size_t)HID*HID, HID, HID);
  transpose_cvt_k<<<dim3(HID/32, HID/32), b256, 0, stream>>>(wv, wqkvT + (size_t)2*HID*HID, HID, HID);
  // fused QKV: [4096][2048] @ [6144][2048]^T -> Q,K scatter + V^T scatter
  gemm256_k<1><<<dim3(3*HID/256, MROWS/256), b512, 0, stream>>>(xb, wqkvT, 3*HID, HID, nullptr, nullptr, qb);

  rope_k<<<(NB*NHD*SEQ*(HD/2))/256, b256, 0, stream>>>(qb, pos);
  rope_k<<<(NB*NHD*SEQ*(HD/2))/256, b256, 0, stream>>>(kb, pos);

  attn_k<<<dim3(512), b256, 0, stream>>>(qb, kb, vb, xb);

  transpose_cvt_k<<<dim3(HID/32, HID/32), b256, 0, stream>>>(wo, wb, HID, HID);
  gemm256_k<2><<<dim3(HID/256, MROWS/256), b512, 0, stream>>>(xb, wb, HID, HID, x, nullptr, out);  // h

  rmsnorm_k<<<MROWS, b256, 0, stream>>>(out, fsc, xb);  // ff

  transpose_cvt_k<<<dim3(FF/32, HID/32), b256, 0, stream>>>(w1, wb, HID, FF);
  gemm256_k<3><<<dim3(FF/256, MROWS/256), b512, 0, stream>>>(xb, wb, FF, HID, nullptr, nullptr, gb);  // silu(ff@w1)
  transpose_cvt_k<<<dim3(FF/32, HID/32), b256, 0, stream>>>(w3, wb, HID, FF);
  gemm256_k<4><<<dim3(FF/256, MROWS/256), b512, 0, stream>>>(xb, wb, FF, HID, nullptr, gb, gb);      // u = silu*g3
  transpose_cvt_k<<<dim3(HID/32, FF/32), b256, 0, stream>>>(w2, wb, FF, HID);
  gemm256_k<2><<<dim3(HID/256, MROWS/256), b512, 0, stream>>>(gb, wb, HID, FF, out, nullptr, out);   // out = h + u@w2
}

// Round 5
// 876.981 us; speedup vs baseline: 1.1585x; 1.1585x over previous
//
#include <hip/hip_runtime.h>

// Problem constants (fixed by the reference)
#define HID 2048
#define SEQ 2048
#define NB 2
#define NHD 16
#define HD 128
#define FF 5632
#define MROWS 4096  // NB*SEQ

typedef __bf16 bf16x8 __attribute__((ext_vector_type(8)));
typedef float f32x4 __attribute__((ext_vector_type(4)));
typedef unsigned short u16;
typedef unsigned int u32;
typedef unsigned long long u64;

__device__ __forceinline__ u16 f2bf(float f) {
  u32 u = __float_as_uint(f);
  u += 0x7fffu + ((u >> 16) & 1u);   // RNE
  return (u16)(u >> 16);
}
__device__ __forceinline__ float bf2f(u16 h) {
  return __uint_as_float(((u32)h) << 16);
}
__device__ __forceinline__ void gld16(const void* g, void* l) {
  // async global->LDS, 16B per lane; LDS dest = wave-uniform base + lane*16
  __builtin_amdgcn_global_load_lds((__attribute__((address_space(1))) void*)g,
                                   (__attribute__((address_space(3))) void*)l, 16, 0, 0);
}

// ---------------- RMSNorm: fp32 [rows][2048] -> bf16 ----------------
__global__ __launch_bounds__(256) void rmsnorm_k(const float* __restrict__ x,
                                                 const float* __restrict__ sc,
                                                 u16* __restrict__ out) {
  __shared__ float red[4];
  const int row = blockIdx.x, t = threadIdx.x;
  const float4* xr = (const float4*)(x + (size_t)row * HID);
  float4 a = xr[t], b = xr[t + 256];
  float ss = a.x*a.x + a.y*a.y + a.z*a.z + a.w*a.w
           + b.x*b.x + b.y*b.y + b.z*b.z + b.w*b.w;
#pragma unroll
  for (int o = 1; o < 64; o <<= 1) ss += __shfl_xor(ss, o);
  if ((t & 63) == 0) red[t >> 6] = ss;
  __syncthreads();
  float tot = red[0] + red[1] + red[2] + red[3];
  float r = rsqrtf(tot * (1.0f / HID) + 1e-5f);
  const float4* scp = (const float4*)sc;
  float4 s0 = scp[t], s1 = scp[t + 256];
  u32 p0 = (u32)f2bf(a.x*r*s0.x) | ((u32)f2bf(a.y*r*s0.y) << 16);
  u32 p1 = (u32)f2bf(a.z*r*s0.z) | ((u32)f2bf(a.w*r*s0.w) << 16);
  u32 p2 = (u32)f2bf(b.x*r*s1.x) | ((u32)f2bf(b.y*r*s1.y) << 16);
  u32 p3 = (u32)f2bf(b.z*r*s1.z) | ((u32)f2bf(b.w*r*s1.w) << 16);
  u32* op = (u32*)(out + (size_t)row * HID);
  op[t*2] = p0; op[t*2+1] = p1;
  op[512 + t*2] = p2; op[512 + t*2 + 1] = p3;
}

// ------------- transpose+convert: fp32 W[R][C] -> bf16 Wt[C][R] -------------
__global__ __launch_bounds__(256) void transpose_cvt_k(const float* __restrict__ W,
                                                       u16* __restrict__ Wt,
                                                       int R, int C) {
  __shared__ float tile[32][33];
  const int tx = threadIdx.x & 31, ty = threadIdx.x >> 5;
  const int bc = blockIdx.x * 32, br = blockIdx.y * 32;
#pragma unroll
  for (int i = 0; i < 4; ++i)
    tile[ty + i*8][tx] = W[(size_t)(br + ty + i*8) * C + bc + tx];
  __syncthreads();
#pragma unroll
  for (int i = 0; i < 4; ++i)
    Wt[(size_t)(bc + ty + i*8) * R + br + tx] = f2bf(tile[tx][ty + i*8]);
}

// ---------------- RoPE in place on [B*H][S][D] bf16 ----------------
__global__ __launch_bounds__(256) void rope_k(u16* __restrict__ qk, const int* __restrict__ pos) {
  const u32 i = blockIdx.x * 256 + threadIdx.x;  // B*H*S*64 pairs
  const int d2 = i & 63;
  const int s = (i >> 6) & 2047;
  const int bh = i >> 17;
  const int b = bh >> 4;
  const float p = (float)pos[(size_t)b * SEQ + s];
  // inv_freq = theta^(-d2/64) = 2^(-d2 * log2(theta)/64)
  const float ang = p * exp2f(-(float)d2 * 0.2958057589f);
  float sv, cv;
  sincosf(ang, &sv, &cv);
  u32* ptr = (u32*)(qk + ((size_t)bh * SEQ + s) * HD) + d2;
  u32 u = *ptr;
  float x0 = bf2f((u16)(u & 0xffff)), x1 = bf2f((u16)(u >> 16));
  float o0 = x0 * cv - x1 * sv;
  float o1 = x1 * cv + x0 * sv;
  *ptr = (u32)f2bf(o0) | ((u32)f2bf(o1) << 16);
}

// ======== GEMM 128x128 tile, BK=64, 4 waves, 1-barrier counted prefetch ========
// C[M][N] = A[M][K] * Bt[N][K]^T, bf16 in, fp32 acc. K%64==0, M,N%128==0.
// Waves: wr=wid>>1 (M-half), wc=wid&1 (N-half); wave computes 64x64.
// LDS: A,B [128][64] bf16 double-buffered = 64 KiB -> 2 blocks/CU (cross-block
// wave overlap hides barrier/prefetch stalls). Swizzle: byte col ^= (row&7)<<4
// across the 128-B row -> each 8 consecutive lanes of a ds_read_b128 hit 8
// distinct 16B slots (conflict-free). Applied source-side for global_load_lds
// (linear LDS dest, m104/m173) and on ds_read addresses.
// Schedule per K-tile t: VMW(0) [only the 8 prefetch loads outstanding,
// issued one full tile ago] -> barrier [all waves have tile t; also proves
// all waves finished reading buf^1: their MFMAs drained lgkmcnt pre-barrier]
// -> issue 8 stages for t+1 into buf^1 -> ds_read + 32 MFMA from buf.
// One barrier per 64 K (m97 had 2 per 32 K).
// EPI: 1 = fused QKV scatter (outp=qb; K at +MROWS*HID; V^T at +2*MROWS*HID);
//      2 = fp32 out = addsrc + acc; 3 = bf16 silu(acc); 4 = bf16 mulsrc*acc.
#define VMW(N) asm volatile("s_waitcnt vmcnt(" #N ")" ::: "memory")
#define BARR() do { __builtin_amdgcn_s_barrier(); __builtin_amdgcn_sched_barrier(0); } while (0)

#define STG(NB) do { \
  gld16(ap + (size_t)0*32*K, &Ab[NB][0*2048 + wid*512]); \
  gld16(ap + (size_t)1*32*K, &Ab[NB][1*2048 + wid*512]); \
  gld16(ap + (size_t)2*32*K, &Ab[NB][2*2048 + wid*512]); \
  gld16(ap + (size_t)3*32*K, &Ab[NB][3*2048 + wid*512]); \
  gld16(bp + (size_t)0*32*K, &Bb[NB][0*2048 + wid*512]); \
  gld16(bp + (size_t)1*32*K, &Bb[NB][1*2048 + wid*512]); \
  gld16(bp + (size_t)2*32*K, &Bb[NB][2*2048 + wid*512]); \
  gld16(bp + (size_t)3*32*K, &Bb[NB][3*2048 + wid*512]); \
} while (0)

#define RDA(BF, CK) do { \
  const char* pa_ = (const char*)Ab[BF] + (wr*64 + lr)*128 + (CK); \
  av[0] = *(const bf16x8*)(pa_);          av[1] = *(const bf16x8*)(pa_ + 2048); \
  av[2] = *(const bf16x8*)(pa_ + 4096);   av[3] = *(const bf16x8*)(pa_ + 6144); \
} while (0)
#define RDB(BF, CK) do { \
  const char* pb_ = (const char*)Bb[BF] + (wc*64 + lr)*128 + (CK); \
  bv[0] = *(const bf16x8*)(pb_);          bv[1] = *(const bf16x8*)(pb_ + 2048); \
  bv[2] = *(const bf16x8*)(pb_ + 4096);   bv[3] = *(const bf16x8*)(pb_ + 6144); \
} while (0)
#define MMA16() do { \
  __builtin_amdgcn_s_setprio(1); \
  _Pragma("unroll") \
  for (int m_ = 0; m_ < 4; ++m_) \
    _Pragma("unroll") \
    for (int n_ = 0; n_ < 4; ++n_) \
      acc[m_][n_] = __builtin_amdgcn_mfma_f32_16x16x32_bf16(av[m_], bv[n_], acc[m_][n_], 0, 0, 0); \
  __builtin_amdgcn_s_setprio(0); \
} while (0)

template <int EPI>
__global__ __launch_bounds__(256, 2) void gemm_k(const u16* __restrict__ A,
                                                 const u16* __restrict__ Bt,
                                                 int N, int K,
                                                 const float* __restrict__ addsrc,
                                                 const u16* __restrict__ mulsrc,
                                                 void* __restrict__ outp) {
  __shared__ __align__(16) u16 Ab[2][128 * 64];
  __shared__ __align__(16) u16 Bb[2][128 * 64];
  const int tid = threadIdx.x, lane = tid & 63, wid = tid >> 6;
  const int lr = lane & 15, lg = lane >> 4;
  const int wr = wid >> 1, wc = wid & 1;

  // XCD swizzle (all grids here have nwg % 8 == 0 -> bijective): XCD x gets a
  // contiguous n-major chunk -> A-panel + B-panel reuse within an XCD L2.
  const int gx = gridDim.x;
  int bid = blockIdx.y * gx + blockIdx.x;
  const int q8 = (gx * gridDim.y) >> 3;
  bid = (bid & 7) * q8 + (bid >> 3);
  const int mt = (bid / gx) * 128, nt = (bid % gx) * 128;

  const f32x4 fz = {0.f, 0.f, 0.f, 0.f};
  f32x4 acc[4][4];
#pragma unroll
  for (int i = 0; i < 4; ++i)
#pragma unroll
    for (int j = 0; j < 4; ++j) acc[i][j] = fz;

  // staging: thread covers LDS bytes tid*16 of each 4KB issue-region.
  // LDS row = j*32 + (tid>>3), col byte = (tid&7)*16; source col pre-swizzled
  // by (row&7)<<4 (row&7 == (tid>>3)&7, j*32 doesn't change it).
  const int srow = tid >> 3;
  const int scol = ((((tid & 7) << 4) ^ ((srow & 7) << 4)) >> 1);
  const u16* ap = A  + (size_t)(mt + srow) * K + scol;
  const u16* bp = Bt + (size_t)(nt + srow) * K + scol;

  // fragment ds_read: row (w*64 + mi*16 + lr), col byte (kk*64+lg*16)^((lr&7)<<4)
  const int swl = (lr & 7) << 4;
  const int ck0 = (lg * 16) ^ swl;
  const int ck1 = (64 + lg * 16) ^ swl;

  bf16x8 av[4], bv[4];

  STG(0);                      // prologue: tile 0 -> buf 0
  ap += 64; bp += 64;

  const int ntk = K >> 6;
  int buf = 0;
  for (int t = 0; t < ntk; ++t) {
    VMW(0);                    // own 8 prefetch loads (issued one tile ago)
    BARR();                    // tile t staged everywhere; buf^1 free to fill
    if (t + 1 < ntk) {
      STG(buf ^ 1);
      ap += 64; bp += 64;
    }
    RDA(buf, ck0); RDB(buf, ck0); MMA16();
    RDA(buf, ck1); RDB(buf, ck1); MMA16();
    buf ^= 1;
  }

  // ---- epilogue ----
#pragma unroll
  for (int mi = 0; mi < 4; ++mi) {
#pragma unroll
    for (int ni = 0; ni < 4; ++ni) {
      const int gr0 = mt + wr * 64 + mi * 16 + lg * 4;
      const int gc = nt + wc * 64 + ni * 16 + lr;
      f32x4 v = acc[mi][ni];
      if (EPI == 1) {
        const int which = gc >> 11;        // 0=Q, 1=K, 2=V (uniform per block)
        const int c2 = gc & 2047;
        const int hh = c2 >> 7, d = c2 & 127;
        if (which < 2) {
          u16* dst = (u16*)outp + (size_t)which * ((size_t)MROWS * HID);
#pragma unroll
          for (int r = 0; r < 4; ++r) {
            const int gr = gr0 + r;
            const int b = gr >> 11, s = gr & 2047;
            dst[((((size_t)(b * NHD + hh)) * SEQ + s) << 7) + d] = f2bf(v[r]);
          }
        } else {
          u16* dst = (u16*)outp + (size_t)2 * ((size_t)MROWS * HID);
          const int b = gr0 >> 11, s0 = gr0 & 2047;
          u64 pk = (u64)f2bf(v[0]) | ((u64)f2bf(v[1]) << 16)
                 | ((u64)f2bf(v[2]) << 32) | ((u64)f2bf(v[3]) << 48);
          *(u64*)(dst + ((((size_t)(b * NHD + hh)) * HD + d) << 11) + s0) = pk;
        }
      } else {
#pragma unroll
        for (int r = 0; r < 4; ++r) {
          const int gr = gr0 + r;
          const float val = v[r];
          if (EPI == 2) {
            const size_t o = (size_t)gr * N + gc;
            ((float*)outp)[o] = addsrc[o] + val;
          } else if (EPI == 3) {
            const size_t o = (size_t)gr * N + gc;
            ((u16*)outp)[o] = f2bf(val / (1.f + __expf(-val)));
          } else if (EPI == 4) {
            const size_t o = (size_t)gr * N + gc;
            ((u16*)outp)[o] = f2bf(bf2f(mulsrc[o]) * val);
          }
        }
      }
    }
  }
}

// ---------------- Flash attention, causal, bf16 ----------------
// Q,K in [B*H][S][D]; V in [B*H][D][S] (transposed by gemm epilogue).
// 512 blocks x 4 waves; block handles q-tile pair (p, 31-p) of one head ->
// uniform 33 key-tiles/block. K/V^T double-buffered LDS via global_load_lds
// with XOR-swizzled source, swizzled ds_reads. 2-phase, counted prefetch.
// P buffer stride = 72 u16 (row length 64 keys + 8 pad) — stride MUST be >= 64.
#define ATT_SW(row) (((row) & 7) << 4)

__device__ __forceinline__ void att_stage(const u16* __restrict__ Kp,
                                          const u16* __restrict__ Vp,
                                          int kt, char* kb, char* vb,
                                          int tid, int wid) {
  // K tile [64 key][128 d] u16 = 16KB: 16 chunks(16B)/row
#pragma unroll
  for (int j = 0; j < 4; ++j) {
    const int c = j * 256 + tid;
    const int row = c >> 4;
    const int scb = ((c & 15) << 4) ^ ATT_SW(row);
    gld16(Kp + (size_t)(kt + row) * HD + (scb >> 1), kb + j * 4096 + wid * 1024);
  }
  // V^T tile [128 d][64 key] u16 = 16KB: 8 chunks/row
#pragma unroll
  for (int j = 0; j < 4; ++j) {
    const int c = j * 256 + tid;
    const int row = c >> 3;
    const int scb = ((c & 7) << 4) ^ ATT_SW(row);
    gld16(Vp + (size_t)row * SEQ + kt + (scb >> 1), vb + j * 4096 + wid * 1024);
  }
}

__global__ __launch_bounds__(256, 2) void attn_k(const u16* __restrict__ Q,
                                                 const u16* __restrict__ Kg,
                                                 const u16* __restrict__ Vtg,
                                                 u16* __restrict__ out) {
  __shared__ __align__(16) char Kb[2][16384];
  __shared__ __align__(16) char Vb[2][16384];
  __shared__ __align__(16) u16 Pl[4][16 * 72];  // per-wave P [q][key], stride 72
  const int tid = threadIdx.x, lane = tid & 63, wid = tid >> 6;
  const int lr = lane & 15, lg = lane >> 4;
  int wg = blockIdx.x;
  wg = (wg & 7) * 64 + (wg >> 3);
  const int bh = wg >> 4, pr = wg & 15;
  const size_t bhoff = (size_t)bh * SEQ * HD;
  const u16* Qp = Q + bhoff;
  const u16* Kp = Kg + bhoff;
  const u16* Vp = Vtg + bhoff;   // [D][S]
  const int bb = bh >> 4, hh = bh & 15;
  u16* Pw = Pl[wid];
  const int sw = ATT_SW(lr);
  const float scale = 0.08838834764831845f;  // 1/sqrt(128)
  const f32x4 fz = {0.f, 0.f, 0.f, 0.f};

  for (int side = 0; side < 2; ++side) {
    const int qt = side ? (31 - pr) : pr;
    const int qrow0 = qt * 64 + wid * 16;

    bf16x8 qf[4];
#pragma unroll
    for (int t = 0; t < 4; ++t)
      qf[t] = *(const bf16x8*)(Qp + (size_t)(qrow0 + lr) * HD + t * 32 + lg * 8);

    f32x4 o[8];
#pragma unroll
    for (int i = 0; i < 8; ++i) o[i] = fz;
    float mrun[4] = {-1e30f, -1e30f, -1e30f, -1e30f};
    float lrun[4] = {0.f, 0.f, 0.f, 0.f};

    const int kend = qt * 64 + 64;
    int cur = 0;
    att_stage(Kp, Vp, 0, Kb[0], Vb[0], tid, wid);
    __syncthreads();  // drains vmcnt -> tile 0 staged

    for (int kt = 0; kt < kend; kt += 64) {
      if (kt + 64 < kend)
        att_stage(Kp, Vp, kt + 64, Kb[cur ^ 1], Vb[cur ^ 1], tid, wid);
      const char* kbuf = Kb[cur];
      const char* vbuf = Vb[cur];

      // ---- QK^T from swizzled LDS ----
      f32x4 sc2[4];
#pragma unroll
      for (int nh = 0; nh < 4; ++nh) {
        f32x4 s = fz;
#pragma unroll
        for (int t = 0; t < 4; ++t) {
          bf16x8 kf = *(const bf16x8*)(kbuf + (nh * 16 + lr) * 256 + ((t * 64 + lg * 16) ^ sw));
          s = __builtin_amdgcn_mfma_f32_16x16x32_bf16(qf[t], kf, s, 0, 0, 0);
        }
        sc2[nh] = s;
      }

      // ---- online softmax over 64 keys (16-lane groups hold keys) ----
      float pv[4][4], alpha[4];
#pragma unroll
      for (int r = 0; r < 4; ++r) {
        const int qrow = qrow0 + lg * 4 + r;
        float s0 = sc2[0][r] * scale;
        float s1 = sc2[1][r] * scale;
        float s2 = sc2[2][r] * scale;
        float s3 = sc2[3][r] * scale;
        if (kt + lr > qrow)      s0 = -1e30f;
        if (kt + 16 + lr > qrow) s1 = -1e30f;
        if (kt + 32 + lr > qrow) s2 = -1e30f;
        if (kt + 48 + lr > qrow) s3 = -1e30f;
        float mx = fmaxf(fmaxf(s0, s1), fmaxf(s2, s3));
        mx = fmaxf(mx, __shfl_xor(mx, 1));
        mx = fmaxf(mx, __shfl_xor(mx, 2));
        mx = fmaxf(mx, __shfl_xor(mx, 4));
        mx = fmaxf(mx, __shfl_xor(mx, 8));
        const float mn = fmaxf(mrun[r], mx);
        const float p0 = __expf(s0 - mn), p1 = __expf(s1 - mn);
        const float p2 = __expf(s2 - mn), p3 = __expf(s3 - mn);
        float ts = p0 + p1 + p2 + p3;
        ts += __shfl_xor(ts, 1);
        ts += __shfl_xor(ts, 2);
        ts += __shfl_xor(ts, 4);
        ts += __shfl_xor(ts, 8);
        const float al = __expf(mrun[r] - mn);
        alpha[r] = al;
        lrun[r] = lrun[r] * al + ts;
        mrun[r] = mn;
        pv[0][r] = p0; pv[1][r] = p1; pv[2][r] = p2; pv[3][r] = p3;
      }
#pragma unroll
      for (int i = 0; i < 8; ++i) {
        o[i][0] *= alpha[0]; o[i][1] *= alpha[1];
        o[i][2] *= alpha[2]; o[i][3] *= alpha[3];
      }

      // ---- P -> LDS (lane redistribution for MFMA A-operand) ----
#pragma unroll
      for (int nh = 0; nh < 4; ++nh)
#pragma unroll
        for (int r = 0; r < 4; ++r)
          Pw[(lg * 4 + r) * 72 + nh * 16 + lr] = f2bf(pv[nh][r]);
      asm volatile("s_waitcnt lgkmcnt(0)\n" ::: "memory");  // P write -> read, same wave
      const bf16x8 pf0 = *(const bf16x8*)(Pw + lr * 72 + lg * 8);
      const bf16x8 pf1 = *(const bf16x8*)(Pw + lr * 72 + 32 + lg * 8);

      // ---- PV from swizzled V^T LDS ----
#pragma unroll
      for (int nt2 = 0; nt2 < 8; ++nt2) {
        const char* vr = vbuf + (nt2 * 16 + lr) * 128;
        bf16x8 v0 = *(const bf16x8*)(vr + ((lg * 16) ^ sw));
        bf16x8 v1 = *(const bf16x8*)(vr + ((64 + lg * 16) ^ sw));
        o[nt2] = __builtin_amdgcn_mfma_f32_16x16x32_bf16(pf0, v0, o[nt2], 0, 0, 0);
        o[nt2] = __builtin_amdgcn_mfma_f32_16x16x32_bf16(pf1, v1, o[nt2], 0, 0, 0);
      }
      __syncthreads();  // next tile staged + buf free for overwrite
      cur ^= 1;
    }

    // ---- epilogue: normalize + store 16 q-rows/wave ----
#pragma unroll
    for (int r = 0; r < 4; ++r) {
      const int q = qrow0 + lg * 4 + r;
      const float inv = 1.f / lrun[r];
      u16* op = out + ((size_t)(bb * SEQ + q)) * HID + hh * HD + lr;
#pragma unroll
      for (int nt2 = 0; nt2 < 8; ++nt2)
        op[nt2 * 16] = f2bf(o[nt2][r] * inv);
    }
  }
}

extern "C" void kernel_launch(void* const* d_in, const int* in_sizes, int n_in,
                              void* d_out, int out_size, void* d_ws, size_t ws_size,
                              hipStream_t stream) {
  (void)in_sizes; (void)n_in; (void)out_size; (void)ws_size;
  const float* x   = (const float*)d_in[0];
  const int*   pos = (const int*)d_in[1];
  // d_in[2] = mask: causal tril by construction — handled analytically
  const float* wq  = (const float*)d_in[3];
  const float* wk  = (const float*)d_in[4];
  const float* wv  = (const float*)d_in[5];
  const float* wo  = (const float*)d_in[6];
  const float* asc = (const float*)d_in[7];
  const float* fsc = (const float*)d_in[8];
  const float* w1  = (const float*)d_in[9];
  const float* w3  = (const float*)d_in[10];
  const float* w2  = (const float*)d_in[11];
  float* out = (float*)d_out;

  // workspace carve (~136 MB)
  char* ws = (char*)d_ws;
  u16* qb = (u16*)ws; ws += (size_t)MROWS * HID * 2;   // Q [B,H,S,D]
  u16* kb = (u16*)ws; ws += (size_t)MROWS * HID * 2;   // K [B,H,S,D]  (must follow qb)
  u16* vb = (u16*)ws; ws += (size_t)MROWS * HID * 2;   // V^T [B,H,D,S] (must follow kb)
  u16* xb = (u16*)ws; ws += (size_t)MROWS * HID * 2;   // x_norm / attn_out / ff (bf16)
  u16* gb = (u16*)ws; ws += (size_t)MROWS * FF * 2;    // g1 / u (bf16)
  u16* wb = (u16*)ws; ws += (size_t)FF * HID * 2;      // current transposed weight (bf16)
  // fused QKV weight [6144][2048] overlaps gb (dead until FFN phase): 25.2MB <= 46.1MB
  u16* wqkvT = gb;

  dim3 b256(256);

  rmsnorm_k<<<MROWS, b256, 0, stream>>>(x, asc, xb);

  transpose_cvt_k<<<dim3(HID/32, HID/32), b256, 0, stream>>>(wq, wqkvT, HID, HID);
  transpose_cvt_k<<<dim3(HID/32, HID/32), b256, 0, stream>>>(wk, wqkvT + (size_t)HID*HID, HID, HID);
  transpose_cvt_k<<<dim3(HID/32, HID/32), b256, 0, stream>>>(wv, wqkvT + (size_t)2*HID*HID, HID, HID);
  // fused QKV: [4096][2048] @ [6144][2048]^T -> Q,K scatter + V^T scatter
  gemm_k<1><<<dim3(3*HID/128, MROWS/128), b256, 0, stream>>>(xb, wqkvT, 3*HID, HID, nullptr, nullptr, qb);

  rope_k<<<(NB*NHD*SEQ*(HD/2))/256, b256, 0, stream>>>(qb, pos);
  rope_k<<<(NB*NHD*SEQ*(HD/2))/256, b256, 0, stream>>>(kb, pos);

  attn_k<<<dim3(512), b256, 0, stream>>>(qb, kb, vb, xb);

  transpose_cvt_k<<<dim3(HID/32, HID/32), b256, 0, stream>>>(wo, wb, HID, HID);
  gemm_k<2><<<dim3(HID/128, MROWS/128), b256, 0, stream>>>(xb, wb, HID, HID, x, nullptr, out);  // h

  rmsnorm_k<<<MROWS, b256, 0, stream>>>(out, fsc, xb);  // ff

  transpose_cvt_k<<<dim3(FF/32, HID/32), b256, 0, stream>>>(w1, wb, HID, FF);
  gemm_k<3><<<dim3(FF/128, MROWS/128), b256, 0, stream>>>(xb, wb, FF, HID, nullptr, nullptr, gb);  // silu(ff@w1)
  transpose_cvt_k<<<dim3(FF/32, HID/32), b256, 0, stream>>>(w3, wb, HID, FF);
  gemm_k<4><<<dim3(FF/128, MROWS/128), b256, 0, stream>>>(xb, wb, FF, HID, nullptr, gb, gb);      // u = silu*g3
  transpose_cvt_k<<<dim3(HID/32, FF/32), b256, 0, stream>>>(w2, wb, FF, HID);
  gemm_k<2><<<dim3(HID/128, MROWS/128), b256, 0, stream>>>(gb, wb, HID, FF, out, nullptr, out);   // out = h + u@w2
}